// Round 10
// baseline (113.446 us; speedup 1.0000x reference)
//
#include <hip/hip_runtime.h>
#include <math.h>

#define BZc 8
#define Cc 512
#define C2c 256
#define HWc 4096
#define OUTC 768
#define NP 1024
#define NQ 3072
#define QG 8        // q groups (chunks) for gemm: 384 q each
#define TAU 5e-5f
#define FIXSLOTS 64

typedef _Float16 h8 __attribute__((ext_vector_type(8)));
typedef float f16v __attribute__((ext_vector_type(16)));
typedef float f32x4 __attribute__((ext_vector_type(4)));

// ---------------- K0: compacted index lists + inverse maps + zero counters -------
__global__ __launch_bounds__(1024) void k_build(const int* __restrict__ mask,
                                                int* __restrict__ pidx,
                                                int* __restrict__ qinv,
                                                int* __restrict__ pinv,
                                                int* __restrict__ cnt) {
    __shared__ int s0[1024], s1[1024], t0[1024], t1[1024];
    int t = threadIdx.x;
    if (t < 8) cnt[t] = 0;
    int f[4];
    int cp = 0;
#pragma unroll
    for (int j = 0; j < 4; ++j) { f[j] = mask[t * 4 + j]; cp += f[j]; }
    s0[t] = cp; s1[t] = 4 - cp;
    __syncthreads();
    int *a = s0, *b = s1, *c = t0, *d = t1;
    for (int off = 1; off < 1024; off <<= 1) {
        int vp = a[t] + (t >= off ? a[t - off] : 0);
        int vq = b[t] + (t >= off ? b[t - off] : 0);
        c[t] = vp; d[t] = vq;
        __syncthreads();
        int* tmp;
        tmp = a; a = c; c = tmp;
        tmp = b; b = d; d = tmp;
    }
    int ep = a[t] - cp;
    int eq = b[t] - (4 - cp);
#pragma unroll
    for (int j = 0; j < 4; ++j) {
        int idx = t * 4 + j;
        if (f[j]) { pidx[ep] = idx; pinv[idx] = ep; qinv[idx] = -1; ep++; }
        else      { qinv[idx] = eq; pinv[idx] = -1; eq++; }
    }
}

// ---------------- K1: prep v4 — all loads upfront, REGULAR stores (NT A/B) -------
__global__ __launch_bounds__(256) void k_prep(const float* __restrict__ x,
                                              const int* __restrict__ pinv,
                                              const int* __restrict__ qinv,
                                              _Float16* __restrict__ latH,
                                              _Float16* __restrict__ latL,
                                              _Float16* __restrict__ forH,
                                              _Float16* __restrict__ forL,
                                              float* __restrict__ invn,
                                              float* __restrict__ invnC,
                                              float* __restrict__ out) {
    int id = blockIdx.x;
    bool isLat = id < 1024;
    int rid = isLat ? id : id - 1024;
    int b = rid >> 7;
    int g = rid & 127;           // 32-col group
    int col0 = g * 32;
    int tid = threadIdx.x;
    __shared__ float tile[64][33];   // [local ch][col]
    __shared__ float ssq[32][33];
    __shared__ int rowm[32];
    if (tid < 32) rowm[tid] = isLat ? qinv[col0 + tid] : pinv[col0 + tid];
    const float* xb = x + (size_t)b * Cc * HWc + (isLat ? (size_t)C2c * HWc : 0);
    float* ob = out + (size_t)b * OUTC * HWc + (isLat ? (size_t)C2c * HWc : 0);
    _Float16* dH = isLat ? latH + (size_t)b * NQ * 256 : forH + (size_t)b * NP * 256;
    _Float16* dL = isLat ? latL + (size_t)b * NQ * 256 : forL + (size_t)b * NP * 256;

    int cr = tid >> 3;           // 0..31: channel row within 32-ch half
    int c4 = (tid & 7) * 4;      // column quad (0..28)

    // prologue: issue ALL 8 staged loads (max MLP)
    f32x4 vv[4][2];
#pragma unroll
    for (int c = 0; c < 4; ++c) {
        vv[c][0] = *(const f32x4*)(xb + (size_t)(c * 64 + cr) * HWc + col0 + c4);
        vv[c][1] = *(const f32x4*)(xb + (size_t)(c * 64 + 32 + cr) * HWc + col0 + c4);
    }
    __syncthreads();             // rowm visible

    int qq = tid >> 3, sub = tid & 7;
    int dr = rowm[qq];

#pragma unroll
    for (int c = 0; c < 4; ++c) {
        int ch0 = c * 64;
        {
            f32x4 v0 = vv[c][0], v1 = vv[c][1];
            tile[cr][c4]      = v0.x; tile[cr][c4 + 1]      = v0.y;
            tile[cr][c4 + 2]  = v0.z; tile[cr][c4 + 3]      = v0.w;
            tile[32 + cr][c4] = v1.x; tile[32 + cr][c4 + 1] = v1.y;
            tile[32 + cr][c4 + 2] = v1.z; tile[32 + cr][c4 + 3] = v1.w;
        }
        __syncthreads();
        // split: thread (qq, sub) emits 8 ch (one h8 hi/lo pair) for column qq
        if (dr >= 0) {
            h8 hv, lv;
#pragma unroll
            for (int j = 0; j < 8; ++j) {
                float v = tile[sub * 8 + j][qq];
                _Float16 h = (_Float16)v;
                hv[j] = h; lv[j] = (_Float16)((v - (float)h) * 2048.0f);
            }
            size_t o = (size_t)dr * 256 + ch0 + sub * 8;
            *(h8*)(dH + o) = hv;
            *(h8*)(dL + o) = lv;
        }
        __syncthreads();
    }

    // epilogue: deferred out-copy with REGULAR stores (A/B vs nontemporal)
#pragma unroll
    for (int c = 0; c < 4; ++c) {
        *(f32x4*)(ob + (size_t)(c * 64 + cr) * HWc + col0 + c4) = vv[c][0];
        *(f32x4*)(ob + (size_t)(c * 64 + 32 + cr) * HWc + col0 + c4) = vv[c][1];
    }

    if (isLat) {
        float s0 = 0.f, s1 = 0.f, s2 = 0.f, s3 = 0.f;
#pragma unroll
        for (int c = 0; c < 4; ++c)
#pragma unroll
            for (int p = 0; p < 2; ++p) {
                f32x4 v = vv[c][p];
                s0 = fmaf(v.x, v.x, s0); s1 = fmaf(v.y, v.y, s1);
                s2 = fmaf(v.z, v.z, s2); s3 = fmaf(v.w, v.w, s3);
            }
        ssq[cr][c4] = s0; ssq[cr][c4 + 1] = s1; ssq[cr][c4 + 2] = s2; ssq[cr][c4 + 3] = s3;
        __syncthreads();
        if (tid < 32) {
            float s = 0.f;
#pragma unroll
            for (int r = 0; r < 32; ++r) s += ssq[r][tid];
            float inv = 1.0f / (sqrtf(s) + 1e-8f);
            invn[b * HWc + col0 + tid] = inv;
            int qc = rowm[tid];
            if (qc >= 0) invnC[b * NQ + qc] = inv;
        }
    } else {
        // zero the shift region for my 32 columns (scatter overwrites masked later)
        f32x4 z = {0.f, 0.f, 0.f, 0.f};
        float* sb = out + (size_t)b * OUTC * HWc + (size_t)Cc * HWc;
        for (int i = tid; i < 256 * 8; i += 256) {
            int ch = i >> 3, j4 = i & 7;
            *(f32x4*)(sb + (size_t)ch * HWc + col0 + j4 * 4) = z;
        }
    }
}

// ---------------- K2: MFMA fp16x2 GEMM (raw) + invn epilogue + per-chunk top-2 ---
__global__ __launch_bounds__(512, 2) void k_gemm(const _Float16* __restrict__ latH,
                                                 const _Float16* __restrict__ latL,
                                                 const _Float16* __restrict__ forH,
                                                 const _Float16* __restrict__ forL,
                                                 const float* __restrict__ invnC,
                                                 float* __restrict__ bv1,
                                                 int* __restrict__ bi1,
                                                 float* __restrict__ bv2) {
    int pg = blockIdx.x;
    int qg = blockIdx.y;
    int b  = blockIdx.z;
    int tid = threadIdx.x;
    int w = tid >> 6, lane = tid & 63;
    int l31 = lane & 31, lh = lane >> 5;

    __shared__ __align__(16) _Float16 sH[2][32 * 256];
    __shared__ __align__(16) _Float16 sL[2][32 * 256];
    __shared__ float sInv[384];

    if (tid < 384) sInv[tid] = invnC[b * NQ + qg * 384 + tid];

    size_t fo = ((size_t)(b * NP + pg * 256 + w * 32 + l31)) * 256 + lh * 8;
    const _Float16* fH = forH + fo;
    const _Float16* fL = forL + fo;
    h8 BH[16], BL[16];
#pragma unroll
    for (int ks = 0; ks < 16; ++ks) {
        BH[ks] = *(const h8*)(fH + ks * 16);
        BL[ks] = *(const h8*)(fL + ks * 16);
    }

    const _Float16* latHb = latH + (size_t)(b * NQ + qg * 384) * 256;
    const _Float16* latLb = latL + (size_t)(b * NQ + qg * 384) * 256;
    int sq0 = tid >> 5;
    int sq1 = 16 + (tid >> 5);
    int ssl = tid & 31;

    float v1 = -INFINITY, v2 = -INFINITY; int i1 = 0;

    f32x4 rH0, rH1, rL0, rL1;
#define LOADQ(t)                                                                   \
    rH0 = *(const f32x4*)(latHb + ((size_t)((t) * 32 + sq0) * 256 + ssl * 8));     \
    rH1 = *(const f32x4*)(latHb + ((size_t)((t) * 32 + sq1) * 256 + ssl * 8));     \
    rL0 = *(const f32x4*)(latLb + ((size_t)((t) * 32 + sq0) * 256 + ssl * 8));     \
    rL1 = *(const f32x4*)(latLb + ((size_t)((t) * 32 + sq1) * 256 + ssl * 8));
#define WRITEQ(bf)                                                                 \
    *(f32x4*)(&sH[bf][sq0 * 256 + ((ssl ^ sq0) * 8)]) = rH0;                       \
    *(f32x4*)(&sH[bf][sq1 * 256 + ((ssl ^ sq1) * 8)]) = rH1;                       \
    *(f32x4*)(&sL[bf][sq0 * 256 + ((ssl ^ sq0) * 8)]) = rL0;                       \
    *(f32x4*)(&sL[bf][sq1 * 256 + ((ssl ^ sq1) * 8)]) = rL1;

    LOADQ(0); WRITEQ(0);
    __syncthreads();

    for (int t = 0; t < 12; ++t) {
        if (t < 11) { LOADQ(t + 1); }
        const _Float16* bufH = &sH[t & 1][0];
        const _Float16* bufL = &sL[t & 1][0];
        f16v accA = {}, accB = {};
#pragma unroll
        for (int ks = 0; ks < 16; ++ks) {
            int slotA = (ks * 2 + lh) ^ l31;
            h8 aH = *(const h8*)(bufH + l31 * 256 + slotA * 8);
            h8 aL = *(const h8*)(bufL + l31 * 256 + slotA * 8);
            accA = __builtin_amdgcn_mfma_f32_32x32x16_f16(aH, BH[ks], accA, 0, 0, 0);
            accB = __builtin_amdgcn_mfma_f32_32x32x16_f16(aH, BL[ks], accB, 0, 0, 0);
            accB = __builtin_amdgcn_mfma_f32_32x32x16_f16(aL, BH[ks], accB, 0, 0, 0);
        }
#pragma unroll
        for (int r = 0; r < 16; ++r) {
            int off = (r & 3) + 8 * (r >> 2) + 4 * lh;
            float v = (accA[r] + accB[r] * (1.0f / 2048.0f)) * sInv[t * 32 + off];
            int q = qg * 384 + t * 32 + off;
            if (v > v1) { v2 = v1; v1 = v; i1 = q; }
            else if (v > v2) { v2 = v; }
        }
        if (t < 11) { WRITEQ((t + 1) & 1); }
        __syncthreads();
    }
#undef LOADQ
#undef WRITEQ
    float ov1 = __shfl_xor(v1, 32);
    int   oi1 = __shfl_xor(i1, 32);
    float ov2 = __shfl_xor(v2, 32);
    if (ov1 > v1) { v2 = fmaxf(v1, ov2); v1 = ov1; i1 = oi1; }
    else          { v2 = fmaxf(ov1, v2); }
    if (lane < 32) {
        size_t o = ((size_t)b * NP + pg * 256 + w * 32 + lane) * QG + qg;
        bv1[o] = v1; bi1[o] = i1; bv2[o] = v2;
    }
}

// ---------------- K3: merge chunks -> best index + margin flag -------------------
__global__ void k_reduce(const float* __restrict__ bv1, const int* __restrict__ bi1,
                         const float* __restrict__ bv2, int* __restrict__ bfin,
                         int* __restrict__ cnt, int* __restrict__ fixrows) {
    int t = blockIdx.x * blockDim.x + threadIdx.x;
    if (t >= BZc * NP) return;
    float V1 = -INFINITY, V2 = -INFINITY; int I1 = 0;
    for (int c = 0; c < QG; ++c) {
        float a = bv1[(size_t)t * QG + c];
        float a2 = bv2[(size_t)t * QG + c];
        int   i = bi1[(size_t)t * QG + c];
        if (a > V1) { V2 = fmaxf(V1, a2); V1 = a; I1 = i; }
        else        { V2 = fmaxf(V2, a); }
    }
    bfin[t] = I1;
    if (V1 - V2 < TAU) {
        int b = t >> 10;
        int s = atomicAdd(&cnt[b], 1);
        if (s < FIXSLOTS) fixrows[b * FIXSLOTS + s] = t & 1023;
    }
}

// ---------------- K4a: exact fp32 fixup, phase A (per q-quarter partial argmax) --
__global__ __launch_bounds__(256) void k_fixA(const float* __restrict__ x,
                                              const int* __restrict__ pidx,
                                              const int* __restrict__ mask,
                                              const float* __restrict__ invn,
                                              const int* __restrict__ cnt,
                                              const int* __restrict__ fixrows,
                                              float* __restrict__ fixv,
                                              int* __restrict__ fixi) {
    int qg = blockIdx.x, s = blockIdx.y, b = blockIdx.z;
    int n = cnt[b]; if (n > FIXSLOTS) n = FIXSLOTS;
    if (s >= n) return;
    int p = fixrows[b * FIXSLOTS + s];
    int porig = pidx[p];
    int tid = threadIdx.x;
    __shared__ float fs[256];
    fs[tid] = x[((size_t)b * Cc + tid) * HWc + porig];
    __syncthreads();
    const float* lx = x + ((size_t)b * Cc + C2c) * HWc;
    int q0 = qg * 1024 + tid * 4;
    float4 acc = make_float4(0.f, 0.f, 0.f, 0.f);
    for (int c0 = 0; c0 < 256; c0 += 8) {
        float4 v[8];
#pragma unroll
        for (int u = 0; u < 8; ++u)
            v[u] = *(const float4*)(lx + (size_t)(c0 + u) * HWc + q0);
#pragma unroll
        for (int u = 0; u < 8; ++u) {
            float fc = fs[c0 + u];
            acc.x = fmaf(fc, v[u].x, acc.x);
            acc.y = fmaf(fc, v[u].y, acc.y);
            acc.z = fmaf(fc, v[u].z, acc.z);
            acc.w = fmaf(fc, v[u].w, acc.w);
        }
    }
    float vals[4] = {acc.x, acc.y, acc.z, acc.w};
    float bv = -INFINITY; int bq = 1 << 30;
#pragma unroll
    for (int k = 0; k < 4; ++k) {
        int q = q0 + k;
        float val = vals[k] * invn[b * HWc + q];
        if (mask[q] == 0 && val > bv) { bv = val; bq = q; }
    }
    __shared__ float rv[256]; __shared__ int rq[256];
    rv[tid] = bv; rq[tid] = bq; __syncthreads();
    for (int off = 128; off > 0; off >>= 1) {
        if (tid < off) {
            float v2 = rv[tid + off]; int q2 = rq[tid + off];
            if (v2 > rv[tid] || (v2 == rv[tid] && q2 < rq[tid])) { rv[tid] = v2; rq[tid] = q2; }
        }
        __syncthreads();
    }
    if (tid == 0) {
        fixv[(b * FIXSLOTS + s) * 4 + qg] = rv[0];
        fixi[(b * FIXSLOTS + s) * 4 + qg] = rq[0];
    }
}

// ---------------- K4b: fixup phase B — merge quarters, spatial->compact ----------
__global__ void k_fixB(const int* __restrict__ cnt, const int* __restrict__ fixrows,
                       const float* __restrict__ fixv, const int* __restrict__ fixi,
                       const int* __restrict__ qinv, int* __restrict__ bfin) {
    int t = threadIdx.x;                 // 512 threads: b = t>>6, s = t&63
    int b = t >> 6, s = t & 63;
    int n = cnt[b]; if (n > FIXSLOTS) n = FIXSLOTS;
    if (s >= n) return;
    float bv = -INFINITY; int bq = 1 << 30;
    for (int qg = 0; qg < 4; ++qg) {
        float v = fixv[(b * FIXSLOTS + s) * 4 + qg];
        int   q = fixi[(b * FIXSLOTS + s) * 4 + qg];
        if (v > bv || (v == bv && q < bq)) { bv = v; bq = q; }
    }
    int p = fixrows[b * FIXSLOTS + s];
    bfin[b * NP + p] = qinv[bq];
}

// ---------------- K5: gather best latter vectors into shift region ---------------
__global__ __launch_bounds__(256) void k_scatter(const _Float16* __restrict__ latH,
                                                 const _Float16* __restrict__ latL,
                                                 const int* __restrict__ bfin,
                                                 const int* __restrict__ pidx,
                                                 float* __restrict__ out) {
    int blk = blockIdx.x;
    int b   = blockIdx.y;
    int tid = threadIdx.x;
    __shared__ float tile[32][257];
    __shared__ int qd[32], pd[32];
    if (tid < 32) {
        qd[tid] = bfin[b * NP + blk * 32 + tid];
        pd[tid] = pidx[blk * 32 + tid];
    }
    __syncthreads();
    for (int i = tid; i < 32 * 256; i += 256) {
        int pp = i >> 8, c = i & 255;
        size_t o = ((size_t)b * NQ + qd[pp]) * 256 + c;
        tile[pp][c] = (float)latH[o] + (float)latL[o] * (1.0f / 2048.0f);
    }
    __syncthreads();
    float* ob = out + (size_t)b * OUTC * HWc + (size_t)Cc * HWc;
    for (int i = tid; i < 256 * 32; i += 256) {
        int ch = i >> 5, j = i & 31;
        ob[(size_t)ch * HWc + pd[j]] = tile[j][ch];
    }
}

extern "C" void kernel_launch(void* const* d_in, const int* in_sizes, int n_in,
                              void* d_out, int out_size, void* d_ws, size_t ws_size,
                              hipStream_t stream) {
    const float* x    = (const float*)d_in[0];
    const int*   mask = (const int*)d_in[1];
    float* out = (float*)d_out;
    char*  ws  = (char*)d_ws;

    _Float16* latH = (_Float16*)(ws);                    // 12,582,912 B
    _Float16* latL = (_Float16*)(ws + 12582912);         // 12,582,912 B
    _Float16* forH = (_Float16*)(ws + 25165824);         //  4,194,304 B
    _Float16* forL = (_Float16*)(ws + 29360128);         //  4,194,304 B
    float* invn    = (float*)(ws + 33554432);            //    131,072 B
    float* invnC   = (float*)(ws + 33685504);            //     98,304 B
    float* bv1     = (float*)(ws + 33783808);            //    262,144 B
    int*   bi1     = (int*)  (ws + 34045952);            //    262,144 B
    float* bv2     = (float*)(ws + 34308096);            //    262,144 B
    int*   bfin    = (int*)  (ws + 34570240);            //     32,768 B
    int*   pidx    = (int*)  (ws + 34603008);            //      4,096 B
    int*   qinv    = (int*)  (ws + 34607104);            //     16,384 B
    int*   pinv    = (int*)  (ws + 34623488);            //     16,384 B
    int*   cnt     = (int*)  (ws + 34639872);            //         32 B
    int*   fixrows = (int*)  (ws + 34639904);            //      2,048 B
    float* fixv    = (float*)(ws + 34641952);            //      8,192 B
    int*   fixi    = (int*)  (ws + 34650144);            //      8,192 B

    k_build<<<1, 1024, 0, stream>>>(mask, pidx, qinv, pinv, cnt);
    k_prep<<<2048, 256, 0, stream>>>(x, pinv, qinv, latH, latL, forH, forL, invn, invnC, out);
    k_gemm<<<dim3(4, QG, BZc), 512, 0, stream>>>(latH, latL, forH, forL, invnC, bv1, bi1, bv2);
    k_reduce<<<(BZc * NP + 255) / 256, 256, 0, stream>>>(bv1, bi1, bv2, bfin, cnt, fixrows);
    k_fixA<<<dim3(4, FIXSLOTS, BZc), 256, 0, stream>>>(x, pidx, mask, invn, cnt, fixrows, fixv, fixi);
    k_fixB<<<1, 512, 0, stream>>>(cnt, fixrows, fixv, fixi, qinv, bfin);
    k_scatter<<<dim3(32, BZc), 256, 0, stream>>>(latH, latL, bfin, pidx, out);
}